// Round 15
// baseline (291.107 us; speedup 1.0000x reference)
//
#include <hip/hip_runtime.h>
#include <hip/hip_cooperative_groups.h>

namespace cg = cooperative_groups;

#define N_NODES 100000
#define N_EDGES 1600000
#define IN_DIM  128
#define HID_DIM 64
#define OUT_DIM 40

#define BUK_SHIFT 9
#define NBUK ((N_NODES + (1 << BUK_SHIFT) - 1) >> BUK_SHIFT)  // 196
#define PART_CHUNK 4096
#define NCH ((N_EDGES + PART_CHUNK - 1) / PART_CHUNK)         // 391
#define CSR_BLOCKS (NCH + 3)                                  // 391 chunks + 2 packW1 + 1 packW2

typedef unsigned short ushort;
typedef unsigned int uint;
typedef __attribute__((ext_vector_type(8))) short bf16x8;
typedef __attribute__((ext_vector_type(4))) float f32x4;

// float -> bf16 bits, round-to-nearest-even
__device__ __forceinline__ ushort f2bf(float x) {
    uint u = __float_as_uint(x);
    uint r = ((u >> 16) & 1u) + 0x7fffu;
    return (ushort)((u + r) >> 16);
}

// ---------------- cooperative CSR build: hist+packs -> scan -> partition -> bucket ----------
// 394 blocks x 512 threads, all phases in one launch (3 launch gaps removed).
__global__ __launch_bounds__(512, 4) void csrbuild_kernel(
        const float* __restrict__ W1, const float* __restrict__ W2,
        ushort* __restrict__ Wb1, ushort* __restrict__ Wb2,
        int* __restrict__ cnt2d,
        const int* __restrict__ src, const int* __restrict__ dst,
        int* __restrict__ bbase, int* __restrict__ cursorA,
        int* __restrict__ rowptr, float* __restrict__ dis,
        uint* __restrict__ buk, int* __restrict__ csr, int n) {
    cg::grid_group grid = cg::this_grid();
    __shared__ int sh[1024];   // union across phases (hist / scan / hist+base / cnt+pre)
    const int blk = blockIdx.x;
    const int t = threadIdx.x;

    // ---- phase 1: per-chunk bucket histograms (blocks 0..390) + W packs (391..393) ----
    if (blk < NCH) {
        for (int i = t; i < NBUK; i += 512) sh[i] = 0;
        __syncthreads();
        const int e0 = blk * PART_CHUNK;
#pragma unroll
        for (int i = 0; i < 8; ++i) {          // 512*8 = 4096
            int e = e0 + t + i * 512;
            if (e < N_EDGES) atomicAdd(&sh[dst[e] >> BUK_SHIFT], 1);
        }
        __syncthreads();
        for (int i = t; i < NBUK; i += 512)
            cnt2d[blk * NBUK + i] = sh[i];
    } else if (blk < NCH + 2) {
        int tt = (blk - NCH) * 512 + t;        // 0..1023: 4 ks * 4 ct * 64
        int lane = tt & 63;
        int ct = (tt >> 6) & 3;
        int ks = tt >> 8;
        int c = ct * 16 + (lane & 15);
        int kb = ks * 32 + ((lane >> 4) << 3);
#pragma unroll
        for (int j = 0; j < 8; ++j)
            Wb1[tt * 8 + j] = f2bf(W1[(kb + j) * HID_DIM + c]);
    } else {
        if (t < 384) {                          // 2 ks * 3 ct * 64
            int lane = t & 63;
            int f = t >> 6;
            int ks = f / 3, ct = f % 3;
            int c = ct * 16 + (lane & 15);
            int kb = ks * 32 + ((lane >> 4) << 3);
#pragma unroll
            for (int j = 0; j < 8; ++j)
                Wb2[t * 8 + j] = (c < OUT_DIM) ? f2bf(W2[(kb + j) * OUT_DIM + c]) : 0;
        }
    }
    grid.sync();

    // ---- phase 2: block 0 sums partial counts (coalesced) + exclusive scan ----
    if (blk == 0) {
        int s = 0;
        if (t < NBUK) {
#pragma unroll 8
            for (int ch = 0; ch < NCH; ++ch) s += cnt2d[ch * NBUK + t];
        }
        if (t < 256) sh[t] = (t < NBUK) ? s : 0;
        __syncthreads();
        for (int off = 1; off < 256; off <<= 1) {
            int v = (t >= off && t < 256) ? sh[t - off] : 0;
            __syncthreads();
            if (t < 256) sh[t] += v;
            __syncthreads();
        }
        if (t < NBUK) {
            int base = (t > 0) ? sh[t - 1] : 0;
            bbase[t] = base;
            cursorA[t] = base;
        }
        if (t == 0) { bbase[NBUK] = N_EDGES; rowptr[n] = N_EDGES; }
    }
    grid.sync();

    // ---- phase 3: partition edges into dst-buckets (blocks 0..390) ----
    if (blk < NCH) {
        int* hist = sh;          // 196
        int* base = sh + 256;    // 196
        for (int i = t; i < NBUK; i += 512) hist[i] = 0;
        __syncthreads();
        int mys[8], myd[8];
        const int e0 = blk * PART_CHUNK;
#pragma unroll
        for (int i = 0; i < 8; ++i) {
            int e = e0 + t + i * 512;
            if (e < N_EDGES) {
                mys[i] = src[e];
                myd[i] = dst[e];
                atomicAdd(&hist[myd[i] >> BUK_SHIFT], 1);
            } else {
                myd[i] = -1;
            }
        }
        __syncthreads();
        for (int i = t; i < NBUK; i += 512)
            base[i] = (hist[i] > 0) ? atomicAdd(&cursorA[i], hist[i]) : 0;
        __syncthreads();
        for (int i = t; i < NBUK; i += 512) hist[i] = 0;
        __syncthreads();
#pragma unroll
        for (int i = 0; i < 8; ++i) {
            if (myd[i] >= 0) {
                int b = myd[i] >> BUK_SHIFT;
                int pos = base[b] + atomicAdd(&hist[b], 1);
                buk[pos] = (uint)mys[i] | ((uint)(myd[i] & 511) << 17);
            }
        }
    }
    grid.sync();

    // ---- phase 4: per-bucket degrees + rowptr + dis + csr fill (blocks 0..195) ----
    if (blk < NBUK) {
        int* cnt = sh;           // 512
        int* pre = sh + 512;     // 512
        const int beg = bbase[blk], end = bbase[blk + 1];
        cnt[t] = 0;
        __syncthreads();
        for (int i = beg + t; i < end; i += 512)
            atomicAdd(&cnt[(buk[i] >> 17) & 511], 1);
        __syncthreads();
        const int c = cnt[t];
        pre[t] = c;
        __syncthreads();
        for (int off = 1; off < 512; off <<= 1) {
            int v = (t >= off) ? pre[t - off] : 0;
            __syncthreads();
            pre[t] += v;
            __syncthreads();
        }
        const int ex = pre[t] - c;
        const int v0 = (blk << BUK_SHIFT) + t;
        if (v0 < n) {
            rowptr[v0] = beg + ex;
            dis[v0] = rsqrtf((float)c + 1.0f);
        }
        __syncthreads();
        cnt[t] = beg + ex;       // per-node csr cursor
        __syncthreads();
        for (int i = beg + t; i < end; i += 512) {
            uint e = buk[i];
            int pos = atomicAdd(&cnt[(e >> 17) & 511], 1);
            csr[pos] = (int)(e & 0x1FFFFu);
        }
    }
}

// ---------------- MFMA GEMM1: ts1(bf16[M][64]) = dis * (X(f32[M][128]) @ W1) ----------------
__global__ __launch_bounds__(256) void mgemm1_kernel(const float* __restrict__ X,
                                                     const ushort* __restrict__ Wb,
                                                     const float* __restrict__ dis,
                                                     ushort* __restrict__ Y, int M) {
    const int wave = threadIdx.x >> 6;
    const int lane = threadIdx.x & 63;
    const int r0 = blockIdx.x * 128 + wave * 32;
    const int la = lane & 15, lb = lane >> 4;

    f32x4 acc[2][4];
#pragma unroll
    for (int i = 0; i < 2; ++i)
#pragma unroll
        for (int j = 0; j < 4; ++j)
#pragma unroll
            for (int r = 0; r < 4; ++r) acc[i][j][r] = 0.0f;

    int ra0 = r0 + la;       if (ra0 >= M) ra0 = M - 1;
    int ra1 = r0 + 16 + la;  if (ra1 >= M) ra1 = M - 1;
    const float* xp0 = X + (long long)ra0 * IN_DIM + lb * 8;
    const float* xp1 = X + (long long)ra1 * IN_DIM + lb * 8;
    const bf16x8* wb = (const bf16x8*)Wb;

#pragma unroll
    for (int ks = 0; ks < 4; ++ks) {
        float4 x00 = *(const float4*)(xp0 + ks * 32);
        float4 x01 = *(const float4*)(xp0 + ks * 32 + 4);
        float4 x10 = *(const float4*)(xp1 + ks * 32);
        float4 x11 = *(const float4*)(xp1 + ks * 32 + 4);
        bf16x8 a0, a1;
        a0[0] = (short)f2bf(x00.x); a0[1] = (short)f2bf(x00.y);
        a0[2] = (short)f2bf(x00.z); a0[3] = (short)f2bf(x00.w);
        a0[4] = (short)f2bf(x01.x); a0[5] = (short)f2bf(x01.y);
        a0[6] = (short)f2bf(x01.z); a0[7] = (short)f2bf(x01.w);
        a1[0] = (short)f2bf(x10.x); a1[1] = (short)f2bf(x10.y);
        a1[2] = (short)f2bf(x10.z); a1[3] = (short)f2bf(x10.w);
        a1[4] = (short)f2bf(x11.x); a1[5] = (short)f2bf(x11.y);
        a1[6] = (short)f2bf(x11.z); a1[7] = (short)f2bf(x11.w);
#pragma unroll
        for (int ct = 0; ct < 4; ++ct) {
            bf16x8 b = wb[(ks * 4 + ct) * 64 + lane];
            acc[0][ct] = __builtin_amdgcn_mfma_f32_16x16x32_bf16(a0, b, acc[0][ct], 0, 0, 0);
            acc[1][ct] = __builtin_amdgcn_mfma_f32_16x16x32_bf16(a1, b, acc[1][ct], 0, 0, 0);
        }
    }

#pragma unroll
    for (int rt = 0; rt < 2; ++rt)
#pragma unroll
        for (int r = 0; r < 4; ++r) {
            int row = r0 + rt * 16 + lb * 4 + r;
            if (row < M) {
                float dv = dis[row];
#pragma unroll
                for (int ct = 0; ct < 4; ++ct)
                    Y[(long long)row * HID_DIM + ct * 16 + la] = f2bf(acc[rt][ct][r] * dv);
            }
        }
}

// ---------------- bf16 unpack-accumulate ----------------
__device__ __forceinline__ void add_bf8(float* acc, uint4 m) {
    acc[0] += __uint_as_float(m.x << 16);
    acc[1] += __uint_as_float(m.x & 0xffff0000u);
    acc[2] += __uint_as_float(m.y << 16);
    acc[3] += __uint_as_float(m.y & 0xffff0000u);
    acc[4] += __uint_as_float(m.z << 16);
    acc[5] += __uint_as_float(m.z & 0xffff0000u);
    acc[6] += __uint_as_float(m.w << 16);
    acc[7] += __uint_as_float(m.w & 0xffff0000u);
}

__device__ __forceinline__ void init_bf8(float* acc, uint4 m) {
    acc[0] = __uint_as_float(m.x << 16);
    acc[1] = __uint_as_float(m.x & 0xffff0000u);
    acc[2] = __uint_as_float(m.y << 16);
    acc[3] = __uint_as_float(m.y & 0xffff0000u);
    acc[4] = __uint_as_float(m.z << 16);
    acc[5] = __uint_as_float(m.z & 0xffff0000u);
    acc[6] = __uint_as_float(m.w << 16);
    acc[7] = __uint_as_float(m.w & 0xffff0000u);
}

// 4-deep pipelined neighbor accumulation (VGPR-light); STRIDE = row stride in uint4
template<int STRIDE>
__device__ __forceinline__ void gather_pipe4(const uint4* __restrict__ tsv,
                                             const int* __restrict__ csr,
                                             int beg, int end, int q, float* acc) {
    int j = beg;
    if (j + 3 < end) {
        int c0 = csr[j], c1 = csr[j + 1], c2 = csr[j + 2], c3 = csr[j + 3];
        j += 4;
        for (; j + 3 < end; j += 4) {
            int n0 = csr[j], n1 = csr[j + 1], n2 = csr[j + 2], n3 = csr[j + 3];
            uint4 m0 = tsv[c0 * STRIDE + q];
            uint4 m1 = tsv[c1 * STRIDE + q];
            uint4 m2 = tsv[c2 * STRIDE + q];
            uint4 m3 = tsv[c3 * STRIDE + q];
            add_bf8(acc, m0); add_bf8(acc, m1); add_bf8(acc, m2); add_bf8(acc, m3);
            c0 = n0; c1 = n1; c2 = n2; c3 = n3;
        }
        uint4 m0 = tsv[c0 * STRIDE + q];
        uint4 m1 = tsv[c1 * STRIDE + q];
        uint4 m2 = tsv[c2 * STRIDE + q];
        uint4 m3 = tsv[c3 * STRIDE + q];
        add_bf8(acc, m0); add_bf8(acc, m1); add_bf8(acc, m2); add_bf8(acc, m3);
    }
    for (; j < end; ++j) add_bf8(acc, tsv[csr[j] * STRIDE + q]);
}

// ---------------- fused: coalesced gather64 (8 thr/node) -> LDS h -> MFMA GEMM2 ----------
// ts2 rows padded to 64 bf16 (128 B, sector-aligned); cols 0-47 written, 0-39 read later.
__global__ __launch_bounds__(256) void fused64_kernel(const int* __restrict__ rowptr,
                                                      const int* __restrict__ csr,
                                                      const ushort* __restrict__ ts,
                                                      const float* __restrict__ dis,
                                                      const float* __restrict__ b1,
                                                      const ushort* __restrict__ Wb2,
                                                      ushort* __restrict__ Y, int n) {
    __shared__ ushort hs[32][72];   // 144 B row stride
    const int t = threadIdx.x;
    const int vloc = t >> 3, q = t & 7;
    const int v = blockIdx.x * 32 + vloc;

    if (v < n) {
        const uint4* tsv = (const uint4*)ts;
        int beg = rowptr[v], end = rowptr[v + 1];
        float acc[8];
        init_bf8(acc, tsv[(long long)v * 8 + q]);   // self-loop term
        gather_pipe4<8>(tsv, csr, beg, end, q, acc);

        float dv = dis[v];
        float4 b0 = ((const float4*)b1)[q * 2];
        float4 bb = ((const float4*)b1)[q * 2 + 1];
        float r0 = fmaxf(acc[0] * dv + b0.x, 0.0f);
        float r1 = fmaxf(acc[1] * dv + b0.y, 0.0f);
        float r2 = fmaxf(acc[2] * dv + b0.z, 0.0f);
        float r3 = fmaxf(acc[3] * dv + b0.w, 0.0f);
        float r4 = fmaxf(acc[4] * dv + bb.x, 0.0f);
        float r5 = fmaxf(acc[5] * dv + bb.y, 0.0f);
        float r6 = fmaxf(acc[6] * dv + bb.z, 0.0f);
        float r7 = fmaxf(acc[7] * dv + bb.w, 0.0f);
        uint4 o;
        o.x = ((uint)f2bf(r1) << 16) | f2bf(r0);
        o.y = ((uint)f2bf(r3) << 16) | f2bf(r2);
        o.z = ((uint)f2bf(r5) << 16) | f2bf(r4);
        o.w = ((uint)f2bf(r7) << 16) | f2bf(r6);
        *(uint4*)&hs[vloc][q * 8] = o;
    } else {
        uint4 z = {0u, 0u, 0u, 0u};
        *(uint4*)&hs[vloc][q * 8] = z;
    }
    __syncthreads();

    if (t < 128) {
        const int wave = t >> 6;           // 0 or 1 -> 16-node tile
        const int lane = t & 63;
        const int la = lane & 15, fg = lane >> 4;
        bf16x8 a0 = *(const bf16x8*)&hs[wave * 16 + la][fg * 8];
        bf16x8 a1 = *(const bf16x8*)&hs[wave * 16 + la][32 + fg * 8];

        const bf16x8* wb = (const bf16x8*)Wb2;
        f32x4 dacc[3];
#pragma unroll
        for (int ct = 0; ct < 3; ++ct)
#pragma unroll
            for (int r = 0; r < 4; ++r) dacc[ct][r] = 0.0f;
#pragma unroll
        for (int ct = 0; ct < 3; ++ct) {
            dacc[ct] = __builtin_amdgcn_mfma_f32_16x16x32_bf16(a0, wb[ct * 64 + lane], dacc[ct], 0, 0, 0);
            dacc[ct] = __builtin_amdgcn_mfma_f32_16x16x32_bf16(a1, wb[(3 + ct) * 64 + lane], dacc[ct], 0, 0, 0);
        }

        const int rbase = blockIdx.x * 32 + wave * 16 + fg * 4;
#pragma unroll
        for (int r = 0; r < 4; ++r) {
            int row = rbase + r;
            if (row < n) {
                float dvr = dis[row];
#pragma unroll
                for (int ct = 0; ct < 3; ++ct)
                    Y[(long long)row * 64 + ct * 16 + la] = f2bf(dacc[ct][r] * dvr);
            }
        }
    }
}

// ---------------- fused gather 40 + log_softmax: block=320 (64 nodes), 4-deep pipeline --------
__global__ __launch_bounds__(320) void gather40ls_kernel(const int* __restrict__ rowptr,
                                                         const int* __restrict__ csr,
                                                         const ushort* __restrict__ ts,
                                                         const float* __restrict__ dis,
                                                         const float* __restrict__ b,
                                                         float* __restrict__ out, int n) {
    __shared__ float smax[64][5];
    __shared__ float ssum[64][5];
    const int t = threadIdx.x;
    const int vloc = t / 5, q = t - vloc * 5;
    const int v = blockIdx.x * 64 + vloc;
    const bool active = (v < n);

    float r[8];
    if (active) {
        const uint4* tsv = (const uint4*)ts;   // row stride 64 bf16 = 8 uint4
        int beg = rowptr[v], end = rowptr[v + 1];
        float acc[8];
        init_bf8(acc, tsv[(long long)v * 8 + q]);
        gather_pipe4<8>(tsv, csr, beg, end, q, acc);

        float dv = dis[v];
        float4 b0 = ((const float4*)b)[q * 2];
        float4 b1 = ((const float4*)b)[q * 2 + 1];
        r[0] = acc[0] * dv + b0.x;
        r[1] = acc[1] * dv + b0.y;
        r[2] = acc[2] * dv + b0.z;
        r[3] = acc[3] * dv + b0.w;
        r[4] = acc[4] * dv + b1.x;
        r[5] = acc[5] * dv + b1.y;
        r[6] = acc[6] * dv + b1.z;
        r[7] = acc[7] * dv + b1.w;
    } else {
#pragma unroll
        for (int i = 0; i < 8; ++i) r[i] = 0.0f;
    }

    float m = r[0];
#pragma unroll
    for (int i = 1; i < 8; ++i) m = fmaxf(m, r[i]);
    smax[vloc][q] = m;
    __syncthreads();
    float gm = fmaxf(fmaxf(fmaxf(smax[vloc][0], smax[vloc][1]), fmaxf(smax[vloc][2], smax[vloc][3])),
                     smax[vloc][4]);
    float s = 0.0f;
#pragma unroll
    for (int i = 0; i < 8; ++i) s += __expf(r[i] - gm);
    ssum[vloc][q] = s;
    __syncthreads();
    float tot = ssum[vloc][0] + ssum[vloc][1] + ssum[vloc][2] + ssum[vloc][3] + ssum[vloc][4];
    float c = gm + __logf(tot);

    if (active) {
        float* rp = out + (long long)v * OUT_DIM + q * 8;
        float4 o0 = { r[0] - c, r[1] - c, r[2] - c, r[3] - c };
        float4 o1 = { r[4] - c, r[5] - c, r[6] - c, r[7] - c };
        ((float4*)rp)[0] = o0;
        ((float4*)rp)[1] = o1;
    }
}

extern "C" void kernel_launch(void* const* d_in, const int* in_sizes, int n_in,
                              void* d_out, int out_size, void* d_ws, size_t ws_size,
                              hipStream_t stream) {
    const float* x  = (const float*)d_in[0];
    const int*   ei = (const int*)d_in[1];
    const float* W1 = (const float*)d_in[2];
    const float* b1 = (const float*)d_in[3];
    const float* W2 = (const float*)d_in[4];
    const float* b2 = (const float*)d_in[5];
    float* out = (float*)d_out;

    const int* src = ei;
    const int* dst = ei + N_EDGES;

    // workspace layout (bytes) — regions verified non-overlapping:
    char* ws = (char*)d_ws;
    int*    rowptr  = (int*)ws;                         // [0, 400,004)
    float*  dis     = (float*)(ws + (512 << 10));       // [512K, +400,000)
    int*    bbase   = (int*)(ws + (1024 << 10));        // 788 B
    int*    cursorA = (int*)(ws + (1028 << 10));        // 784 B
    ushort* Wb1     = (ushort*)(ws + (1036 << 10));     // 16 KB -> 1052K
    ushort* Wb2     = (ushort*)(ws + (1056 << 10));     // 6 KB  -> 1062K
    int*    cnt2d   = (int*)(ws + (1100 << 10));        // 391*196*4 = 306,544 -> ~1400K
    int*    csr     = (int*)(ws + (2048 << 10));        // 6.4 MB -> ~8.3 MB
    char*   p       = ws + (9216 << 10);                // 9 MB
    ushort* ts1     = (ushort*)p;                       // 12.8 MB (bf16 [M][64])
    uint*   buk     = (uint*)p;                         // 6.4 MB, aliases ts1 (dead before mgemm1)
    ushort* ts2     = (ushort*)(p + 12800000);          // 12.8 MB (bf16 [M][64], cols 0-47 used)

    // cooperative CSR build: hist+packs -> scan -> partition -> bucket (one launch)
    int nn = N_NODES;
    void* args[] = { (void*)&W1, (void*)&W2, (void*)&Wb1, (void*)&Wb2, (void*)&cnt2d,
                     (void*)&src, (void*)&dst, (void*)&bbase, (void*)&cursorA,
                     (void*)&rowptr, (void*)&dis, (void*)&buk, (void*)&csr, (void*)&nn };
    hipLaunchCooperativeKernel((void*)csrbuild_kernel, dim3(CSR_BLOCKS), dim3(512),
                               args, 0, stream);

    // layer 1 GEMM
    mgemm1_kernel<<<(N_NODES + 127) / 128, 256, 0, stream>>>(x, Wb1, dis, ts1, N_NODES);

    // fused: coalesced gather64 + relu/bias -> LDS -> GEMM2 -> ts2 (128 B rows)
    fused64_kernel<<<(N_NODES + 31) / 32, 256, 0, stream>>>(rowptr, csr, ts1, dis, b1, Wb2,
                                                            ts2, N_NODES);

    // layer 2 gather + log_softmax
    gather40ls_kernel<<<(N_NODES + 63) / 64, 320, 0, stream>>>(rowptr, csr, ts2, dis, b2,
                                                               out, N_NODES);
}

// Round 17
// 142.641 us; speedup vs baseline: 2.0408x; 2.0408x over previous
//
#include <hip/hip_runtime.h>

#define N_NODES 100000
#define N_EDGES 1600000
#define IN_DIM  128
#define HID_DIM 64
#define OUT_DIM 40

#define BUK_SHIFT 9
#define NBUK ((N_NODES + (1 << BUK_SHIFT) - 1) >> BUK_SHIFT)  // 196
#define PART_CHUNK 4096
#define PART_EPT 16     // PART_CHUNK / 256
#define NCH ((N_EDGES + PART_CHUNK - 1) / PART_CHUNK)         // 391
#define MG_BLOCKS ((N_NODES + 127) / 128)                     // 782
#define PREP_BLOCKS (NCH + 2 + MG_BLOCKS)                     // 1175

typedef unsigned short ushort;
typedef unsigned int uint;
typedef __attribute__((ext_vector_type(8))) short bf16x8;
typedef __attribute__((ext_vector_type(4))) float f32x4;

// float -> bf16 bits, round-to-nearest-even
__device__ __forceinline__ ushort f2bf(float x) {
    uint u = __float_as_uint(x);
    uint r = ((u >> 16) & 1u) + 0x7fffu;
    return (ushort)((u + r) >> 16);
}

// ---------------- merged prep: hist (blk 0..390) + packW2 (391..392) + mgemm1 (393+) --------
// GEMM blocks stage W1 fragments in LDS themselves (no cross-block dependency -> no race).
// mgemm1 output is UNSCALED XW1 (dis applied in fused64), so no dependency on CSR build.
__global__ __launch_bounds__(256) void prepg_kernel(const float* __restrict__ W1,
                                                    const float* __restrict__ W2,
                                                    ushort* __restrict__ Wb2,
                                                    int* __restrict__ cnt2d,
                                                    const int* __restrict__ dst,
                                                    const float* __restrict__ X,
                                                    ushort* __restrict__ ts1, int M) {
    const int blk = blockIdx.x;
    const int t = threadIdx.x;
    if (blk < NCH) {
        __shared__ int h[NBUK];
        for (int i = t; i < NBUK; i += 256) h[i] = 0;
        __syncthreads();
        const int e0 = blk * PART_CHUNK;
#pragma unroll
        for (int i = 0; i < PART_EPT; ++i) {
            int e = e0 + t + i * 256;
            if (e < N_EDGES) atomicAdd(&h[dst[e] >> BUK_SHIFT], 1);
        }
        __syncthreads();
        for (int i = t; i < NBUK; i += 256)
            cnt2d[blk * NBUK + i] = h[i];
    } else if (blk < NCH + 2) {
        int tt = (blk - NCH) * 256 + t;   // 0..511 (384 used): 2 ks * 3 ct * 64
        if (tt < 384) {
            int lane = tt & 63;
            int f = tt >> 6;          // 0..5
            int ks = f / 3, ct = f % 3;
            int c = ct * 16 + (lane & 15);
            int kb = ks * 32 + ((lane >> 4) << 3);
#pragma unroll
            for (int j = 0; j < 8; ++j)
                Wb2[tt * 8 + j] = (c < OUT_DIM) ? f2bf(W2[(kb + j) * OUT_DIM + c]) : 0;
        }
    } else {
        // mgemm1: ts1 = X @ W1 (bf16, UNSCALED). W1 fragments staged in LDS per block.
        __shared__ ushort wlds[16 * 64 * 8];   // 16 KB: frag f, lane l -> [(f*64+l)*8 + j]
        const int gblk = blk - NCH - 2;
        const int wave = t >> 6;
        const int lane = t & 63;
        const int la = lane & 15, lb = lane >> 4;

        // stage: each thread packs 4 fragments (f = t>>6 + {0,4,8,12}) for its lane
#pragma unroll
        for (int i = 0; i < 4; ++i) {
            int f = (t >> 6) + i * 4;         // 0..15
            int ks = f >> 2, ct = f & 3;
            int c = ct * 16 + la;
            int kb = ks * 32 + (lb << 3);
            ushort* wp = &wlds[(f * 64 + lane) * 8];
#pragma unroll
            for (int j = 0; j < 8; ++j)
                wp[j] = f2bf(W1[(kb + j) * HID_DIM + c]);
        }
        __syncthreads();

        const int r0 = gblk * 128 + wave * 32;
        f32x4 acc[2][4];
#pragma unroll
        for (int i = 0; i < 2; ++i)
#pragma unroll
            for (int j = 0; j < 4; ++j)
#pragma unroll
                for (int r = 0; r < 4; ++r) acc[i][j][r] = 0.0f;

        int ra0 = r0 + la;       if (ra0 >= M) ra0 = M - 1;
        int ra1 = r0 + 16 + la;  if (ra1 >= M) ra1 = M - 1;
        const float* xp0 = X + (long long)ra0 * IN_DIM + lb * 8;
        const float* xp1 = X + (long long)ra1 * IN_DIM + lb * 8;
        const bf16x8* wb = (const bf16x8*)wlds;

#pragma unroll
        for (int ks = 0; ks < 4; ++ks) {
            float4 x00 = *(const float4*)(xp0 + ks * 32);
            float4 x01 = *(const float4*)(xp0 + ks * 32 + 4);
            float4 x10 = *(const float4*)(xp1 + ks * 32);
            float4 x11 = *(const float4*)(xp1 + ks * 32 + 4);
            bf16x8 a0, a1;
            a0[0] = (short)f2bf(x00.x); a0[1] = (short)f2bf(x00.y);
            a0[2] = (short)f2bf(x00.z); a0[3] = (short)f2bf(x00.w);
            a0[4] = (short)f2bf(x01.x); a0[5] = (short)f2bf(x01.y);
            a0[6] = (short)f2bf(x01.z); a0[7] = (short)f2bf(x01.w);
            a1[0] = (short)f2bf(x10.x); a1[1] = (short)f2bf(x10.y);
            a1[2] = (short)f2bf(x10.z); a1[3] = (short)f2bf(x10.w);
            a1[4] = (short)f2bf(x11.x); a1[5] = (short)f2bf(x11.y);
            a1[6] = (short)f2bf(x11.z); a1[7] = (short)f2bf(x11.w);
#pragma unroll
            for (int ct = 0; ct < 4; ++ct) {
                bf16x8 b = wb[(ks * 4 + ct) * 64 + lane];
                acc[0][ct] = __builtin_amdgcn_mfma_f32_16x16x32_bf16(a0, b, acc[0][ct], 0, 0, 0);
                acc[1][ct] = __builtin_amdgcn_mfma_f32_16x16x32_bf16(a1, b, acc[1][ct], 0, 0, 0);
            }
        }

#pragma unroll
        for (int rt = 0; rt < 2; ++rt)
#pragma unroll
            for (int r = 0; r < 4; ++r) {
                int row = r0 + rt * 16 + lb * 4 + r;
                if (row < M) {
#pragma unroll
                    for (int ct = 0; ct < 4; ++ct)
                        ts1[(long long)row * HID_DIM + ct * 16 + la] = f2bf(acc[rt][ct][r]);
                }
            }
    }
}

// ---------------- scanB: sum partial counts (coalesced), scan -> bbase, cursorA ----------------
__global__ __launch_bounds__(256) void scanB_kernel(const int* __restrict__ cnt2d,
                                                    int* __restrict__ bbase,
                                                    int* __restrict__ cursorA,
                                                    int* __restrict__ rowptr) {
    __shared__ int sh[256];
    const int t = threadIdx.x;
    int s = 0;
    if (t < NBUK) {
#pragma unroll 8
        for (int ch = 0; ch < NCH; ++ch) s += cnt2d[ch * NBUK + t];
    }
    sh[t] = s;
    __syncthreads();
    for (int off = 1; off < 256; off <<= 1) {
        int v = (t >= off) ? sh[t - off] : 0;
        __syncthreads();
        sh[t] += v;
        __syncthreads();
    }
    if (t < NBUK) {
        int base = (t > 0) ? sh[t - 1] : 0;
        bbase[t] = base;
        cursorA[t] = base;
    }
    if (t == 0) { bbase[NBUK] = N_EDGES; rowptr[N_NODES] = N_EDGES; }
}

// ---------------- pass A: partition edges into dst-buckets (packed uint) ----------------
// entry = src | ((dst & 511) << 17)
__global__ __launch_bounds__(256) void partA_kernel(const int* __restrict__ src,
                                                    const int* __restrict__ dst,
                                                    int* __restrict__ cursorA,
                                                    uint* __restrict__ buk, int E) {
    __shared__ int hist[NBUK];
    __shared__ int base[NBUK];
    const int t = threadIdx.x;
    const int e0 = blockIdx.x * PART_CHUNK;
    for (int i = t; i < NBUK; i += 256) hist[i] = 0;
    __syncthreads();
    int mys[PART_EPT], myd[PART_EPT];
#pragma unroll
    for (int i = 0; i < PART_EPT; ++i) {
        int e = e0 + t + i * 256;
        if (e < E) {
            mys[i] = src[e];
            myd[i] = dst[e];
            atomicAdd(&hist[myd[i] >> BUK_SHIFT], 1);
        } else {
            myd[i] = -1;
        }
    }
    __syncthreads();
    for (int i = t; i < NBUK; i += 256)
        base[i] = (hist[i] > 0) ? atomicAdd(&cursorA[i], hist[i]) : 0;
    __syncthreads();
    for (int i = t; i < NBUK; i += 256) hist[i] = 0;
    __syncthreads();
#pragma unroll
    for (int i = 0; i < PART_EPT; ++i) {
        if (myd[i] >= 0) {
            int b = myd[i] >> BUK_SHIFT;
            int pos = base[b] + atomicAdd(&hist[b], 1);
            buk[pos] = (uint)mys[i] | ((uint)(myd[i] & 511) << 17);
        }
    }
}

// ---------------- per-bucket: node degrees + rowptr + dis + csr fill, all LDS ----------------
__global__ __launch_bounds__(512) void bucket_kernel(const uint* __restrict__ buk,
                                                     const int* __restrict__ bbase,
                                                     int* __restrict__ rowptr,
                                                     float* __restrict__ dis,
                                                     int* __restrict__ csr, int n) {
    __shared__ int cnt[512];
    __shared__ int pre[512];
    const int t = threadIdx.x;
    const int b = blockIdx.x;
    const int beg = bbase[b], end = bbase[b + 1];
    cnt[t] = 0;
    __syncthreads();
    for (int i = beg + t; i < end; i += 512)
        atomicAdd(&cnt[(buk[i] >> 17) & 511], 1);
    __syncthreads();
    const int c = cnt[t];
    pre[t] = c;
    __syncthreads();
    for (int off = 1; off < 512; off <<= 1) {
        int v = (t >= off) ? pre[t - off] : 0;
        __syncthreads();
        pre[t] += v;
        __syncthreads();
    }
    const int ex = pre[t] - c;
    const int v0 = (b << BUK_SHIFT) + t;
    if (v0 < n) {
        rowptr[v0] = beg + ex;
        dis[v0] = rsqrtf((float)c + 1.0f);
    }
    __syncthreads();
    cnt[t] = beg + ex;
    __syncthreads();
    for (int i = beg + t; i < end; i += 512) {
        uint e = buk[i];
        int pos = atomicAdd(&cnt[(e >> 17) & 511], 1);
        csr[pos] = (int)(e & 0x1FFFFu);
    }
}

// ---------------- bf16 unpack helpers ----------------
__device__ __forceinline__ void add_bf8(float* acc, uint4 m) {
    acc[0] += __uint_as_float(m.x << 16);
    acc[1] += __uint_as_float(m.x & 0xffff0000u);
    acc[2] += __uint_as_float(m.y << 16);
    acc[3] += __uint_as_float(m.y & 0xffff0000u);
    acc[4] += __uint_as_float(m.z << 16);
    acc[5] += __uint_as_float(m.z & 0xffff0000u);
    acc[6] += __uint_as_float(m.w << 16);
    acc[7] += __uint_as_float(m.w & 0xffff0000u);
}

__device__ __forceinline__ void init_bf8(float* acc, uint4 m) {
    acc[0] = __uint_as_float(m.x << 16);
    acc[1] = __uint_as_float(m.x & 0xffff0000u);
    acc[2] = __uint_as_float(m.y << 16);
    acc[3] = __uint_as_float(m.y & 0xffff0000u);
    acc[4] = __uint_as_float(m.z << 16);
    acc[5] = __uint_as_float(m.z & 0xffff0000u);
    acc[6] = __uint_as_float(m.w << 16);
    acc[7] = __uint_as_float(m.w & 0xffff0000u);
}

// acc += s * unpack(m)
__device__ __forceinline__ void fma_bf8(float* acc, uint4 m, float s) {
    acc[0] = fmaf(s, __uint_as_float(m.x << 16), acc[0]);
    acc[1] = fmaf(s, __uint_as_float(m.x & 0xffff0000u), acc[1]);
    acc[2] = fmaf(s, __uint_as_float(m.y << 16), acc[2]);
    acc[3] = fmaf(s, __uint_as_float(m.y & 0xffff0000u), acc[3]);
    acc[4] = fmaf(s, __uint_as_float(m.z << 16), acc[4]);
    acc[5] = fmaf(s, __uint_as_float(m.z & 0xffff0000u), acc[5]);
    acc[6] = fmaf(s, __uint_as_float(m.w << 16), acc[6]);
    acc[7] = fmaf(s, __uint_as_float(m.w & 0xffff0000u), acc[7]);
}

// 4-deep pipelined neighbor accumulation (unscaled); STRIDE = row stride in uint4
template<int STRIDE>
__device__ __forceinline__ void gather_pipe4(const uint4* __restrict__ tsv,
                                             const int* __restrict__ csr,
                                             int beg, int end, int q, float* acc) {
    int j = beg;
    if (j + 3 < end) {
        int c0 = csr[j], c1 = csr[j + 1], c2 = csr[j + 2], c3 = csr[j + 3];
        j += 4;
        for (; j + 3 < end; j += 4) {
            int n0 = csr[j], n1 = csr[j + 1], n2 = csr[j + 2], n3 = csr[j + 3];
            uint4 m0 = tsv[c0 * STRIDE + q];
            uint4 m1 = tsv[c1 * STRIDE + q];
            uint4 m2 = tsv[c2 * STRIDE + q];
            uint4 m3 = tsv[c3 * STRIDE + q];
            add_bf8(acc, m0); add_bf8(acc, m1); add_bf8(acc, m2); add_bf8(acc, m3);
            c0 = n0; c1 = n1; c2 = n2; c3 = n3;
        }
        uint4 m0 = tsv[c0 * STRIDE + q];
        uint4 m1 = tsv[c1 * STRIDE + q];
        uint4 m2 = tsv[c2 * STRIDE + q];
        uint4 m3 = tsv[c3 * STRIDE + q];
        add_bf8(acc, m0); add_bf8(acc, m1); add_bf8(acc, m2); add_bf8(acc, m3);
    }
    for (; j < end; ++j) add_bf8(acc, tsv[csr[j] * STRIDE + q]);
}

// 4-deep pipelined neighbor accumulation with per-neighbor dis scale
template<int STRIDE>
__device__ __forceinline__ void gather_pipe4s(const uint4* __restrict__ tsv,
                                              const int* __restrict__ csr,
                                              const float* __restrict__ dis,
                                              int beg, int end, int q, float* acc) {
    int j = beg;
    if (j + 3 < end) {
        int c0 = csr[j], c1 = csr[j + 1], c2 = csr[j + 2], c3 = csr[j + 3];
        j += 4;
        for (; j + 3 < end; j += 4) {
            int n0 = csr[j], n1 = csr[j + 1], n2 = csr[j + 2], n3 = csr[j + 3];
            float d0 = dis[c0], d1 = dis[c1], d2 = dis[c2], d3 = dis[c3];
            uint4 m0 = tsv[c0 * STRIDE + q];
            uint4 m1 = tsv[c1 * STRIDE + q];
            uint4 m2 = tsv[c2 * STRIDE + q];
            uint4 m3 = tsv[c3 * STRIDE + q];
            fma_bf8(acc, m0, d0); fma_bf8(acc, m1, d1);
            fma_bf8(acc, m2, d2); fma_bf8(acc, m3, d3);
            c0 = n0; c1 = n1; c2 = n2; c3 = n3;
        }
        float d0 = dis[c0], d1 = dis[c1], d2 = dis[c2], d3 = dis[c3];
        uint4 m0 = tsv[c0 * STRIDE + q];
        uint4 m1 = tsv[c1 * STRIDE + q];
        uint4 m2 = tsv[c2 * STRIDE + q];
        uint4 m3 = tsv[c3 * STRIDE + q];
        fma_bf8(acc, m0, d0); fma_bf8(acc, m1, d1);
        fma_bf8(acc, m2, d2); fma_bf8(acc, m3, d3);
    }
    for (; j < end; ++j) { int u = csr[j]; fma_bf8(acc, tsv[u * STRIDE + q], dis[u]); }
}

// ---------------- fused: gather64 (dis[u]-scaled, 8 thr/node) -> LDS h -> MFMA GEMM2 --------
// ts1 is UNSCALED XW1; gather applies dis[u] per neighbor, dis[v] in epilogue.
// ts2 rows padded to 64 bf16 (128 B); cols 0-47 written, 0-39 read later.
__global__ __launch_bounds__(256) void fused64_kernel(const int* __restrict__ rowptr,
                                                      const int* __restrict__ csr,
                                                      const ushort* __restrict__ ts,
                                                      const float* __restrict__ dis,
                                                      const float* __restrict__ b1,
                                                      const ushort* __restrict__ Wb2,
                                                      ushort* __restrict__ Y, int n) {
    __shared__ ushort hs[32][72];   // 144 B row stride
    const int t = threadIdx.x;
    const int vloc = t >> 3, q = t & 7;
    const int v = blockIdx.x * 32 + vloc;

    if (v < n) {
        const uint4* tsv = (const uint4*)ts;
        int beg = rowptr[v], end = rowptr[v + 1];
        float dv = dis[v];
        float acc[8] = {0.f, 0.f, 0.f, 0.f, 0.f, 0.f, 0.f, 0.f};
        fma_bf8(acc, tsv[(long long)v * 8 + q], dv);   // self-loop: dis[v]*ts1[v]
        gather_pipe4s<8>(tsv, csr, dis, beg, end, q, acc);

        float4 b0 = ((const float4*)b1)[q * 2];
        float4 bb = ((const float4*)b1)[q * 2 + 1];
        float r0 = fmaxf(acc[0] * dv + b0.x, 0.0f);
        float r1 = fmaxf(acc[1] * dv + b0.y, 0.0f);
        float r2 = fmaxf(acc[2] * dv + b0.z, 0.0f);
        float r3 = fmaxf(acc[3] * dv + b0.w, 0.0f);
        float r4 = fmaxf(acc[4] * dv + bb.x, 0.0f);
        float r5 = fmaxf(acc[5] * dv + bb.y, 0.0f);
        float r6 = fmaxf(acc[6] * dv + bb.z, 0.0f);
        float r7 = fmaxf(acc[7] * dv + bb.w, 0.0f);
        uint4 o;
        o.x = ((uint)f2bf(r1) << 16) | f2bf(r0);
        o.y = ((uint)f2bf(r3) << 16) | f2bf(r2);
        o.z = ((uint)f2bf(r5) << 16) | f2bf(r4);
        o.w = ((uint)f2bf(r7) << 16) | f2bf(r6);
        *(uint4*)&hs[vloc][q * 8] = o;
    } else {
        uint4 z = {0u, 0u, 0u, 0u};
        *(uint4*)&hs[vloc][q * 8] = z;
    }
    __syncthreads();

    if (t < 128) {
        const int wave = t >> 6;           // 0 or 1 -> 16-node tile
        const int lane = t & 63;
        const int la = lane & 15, fg = lane >> 4;
        bf16x8 a0 = *(const bf16x8*)&hs[wave * 16 + la][fg * 8];
        bf16x8 a1 = *(const bf16x8*)&hs[wave * 16 + la][32 + fg * 8];

        const bf16x8* wb = (const bf16x8*)Wb2;
        f32x4 dacc[3];
#pragma unroll
        for (int ct = 0; ct < 3; ++ct)
#pragma unroll
            for (int r = 0; r < 4; ++r) dacc[ct][r] = 0.0f;
#pragma unroll
        for (int ct = 0; ct < 3; ++ct) {
            dacc[ct] = __builtin_amdgcn_mfma_f32_16x16x32_bf16(a0, wb[ct * 64 + lane], dacc[ct], 0, 0, 0);
            dacc[ct] = __builtin_amdgcn_mfma_f32_16x16x32_bf16(a1, wb[(3 + ct) * 64 + lane], dacc[ct], 0, 0, 0);
        }

        const int rbase = blockIdx.x * 32 + wave * 16 + fg * 4;
#pragma unroll
        for (int r = 0; r < 4; ++r) {
            int row = rbase + r;
            if (row < n) {
                float dvr = dis[row];
#pragma unroll
                for (int ct = 0; ct < 3; ++ct)
                    Y[(long long)row * 64 + ct * 16 + la] = f2bf(dacc[ct][r] * dvr);
            }
        }
    }
}

// ---------------- fused gather 40 + log_softmax: block=320 (64 nodes), 4-deep pipeline --------
// ts rows are 64 bf16 (8 uint4) stride; q in [0,5) covers exactly the 40 real cols.
__global__ __launch_bounds__(320) void gather40ls_kernel(const int* __restrict__ rowptr,
                                                         const int* __restrict__ csr,
                                                         const ushort* __restrict__ ts,
                                                         const float* __restrict__ dis,
                                                         const float* __restrict__ b,
                                                         float* __restrict__ out, int n) {
    __shared__ float smax[64][5];
    __shared__ float ssum[64][5];
    const int t = threadIdx.x;
    const int vloc = t / 5, q = t - vloc * 5;
    const int v = blockIdx.x * 64 + vloc;
    const bool active = (v < n);

    float r[8];
    if (active) {
        const uint4* tsv = (const uint4*)ts;   // row stride 64 bf16 = 8 uint4
        int beg = rowptr[v], end = rowptr[v + 1];
        float acc[8];
        init_bf8(acc, tsv[(long long)v * 8 + q]);
        gather_pipe4<8>(tsv, csr, beg, end, q, acc);

        float dv = dis[v];
        float4 b0 = ((const float4*)b)[q * 2];
        float4 b1 = ((const float4*)b)[q * 2 + 1];
        r[0] = acc[0] * dv + b0.x;
        r[1] = acc[1] * dv + b0.y;
        r[2] = acc[2] * dv + b0.z;
        r[3] = acc[3] * dv + b0.w;
        r[4] = acc[4] * dv + b1.x;
        r[5] = acc[5] * dv + b1.y;
        r[6] = acc[6] * dv + b1.z;
        r[7] = acc[7] * dv + b1.w;
    } else {
#pragma unroll
        for (int i = 0; i < 8; ++i) r[i] = 0.0f;
    }

    float m = r[0];
#pragma unroll
    for (int i = 1; i < 8; ++i) m = fmaxf(m, r[i]);
    smax[vloc][q] = m;
    __syncthreads();
    float gm = fmaxf(fmaxf(fmaxf(smax[vloc][0], smax[vloc][1]), fmaxf(smax[vloc][2], smax[vloc][3])),
                     smax[vloc][4]);
    float s = 0.0f;
#pragma unroll
    for (int i = 0; i < 8; ++i) s += __expf(r[i] - gm);
    ssum[vloc][q] = s;
    __syncthreads();
    float tot = ssum[vloc][0] + ssum[vloc][1] + ssum[vloc][2] + ssum[vloc][3] + ssum[vloc][4];
    float c = gm + __logf(tot);

    if (active) {
        float* rp = out + (long long)v * OUT_DIM + q * 8;
        float4 o0 = { r[0] - c, r[1] - c, r[2] - c, r[3] - c };
        float4 o1 = { r[4] - c, r[5] - c, r[6] - c, r[7] - c };
        ((float4*)rp)[0] = o0;
        ((float4*)rp)[1] = o1;
    }
}

extern "C" void kernel_launch(void* const* d_in, const int* in_sizes, int n_in,
                              void* d_out, int out_size, void* d_ws, size_t ws_size,
                              hipStream_t stream) {
    const float* x  = (const float*)d_in[0];
    const int*   ei = (const int*)d_in[1];
    const float* W1 = (const float*)d_in[2];
    const float* b1 = (const float*)d_in[3];
    const float* W2 = (const float*)d_in[4];
    const float* b2 = (const float*)d_in[5];
    float* out = (float*)d_out;

    const int* src = ei;
    const int* dst = ei + N_EDGES;

    // workspace layout (bytes) — regions verified non-overlapping; buk has its own region
    // because ts1 is written (by prepg) BEFORE partA fills buk.
    char* ws = (char*)d_ws;
    int*    rowptr  = (int*)ws;                         // [0, 400,004)
    float*  dis     = (float*)(ws + (512 << 10));       // [512K, +400,000)
    int*    bbase   = (int*)(ws + (1024 << 10));        // 788 B
    int*    cursorA = (int*)(ws + (1028 << 10));        // 784 B
    ushort* Wb2     = (ushort*)(ws + (1056 << 10));     // 6 KB  -> 1062K
    int*    cnt2d   = (int*)(ws + (1100 << 10));        // 306,544 B -> ~1400K
    int*    csr     = (int*)(ws + (2048 << 10));        // 6.4 MB -> ~8.3 MB
    char*   p       = ws + (9216 << 10);                // 9 MB
    ushort* ts1     = (ushort*)p;                       // 12.8 MB (bf16 [M][64], unscaled XW1)
    ushort* ts2     = (ushort*)(p + 12800000);          // 12.8 MB (bf16 [M][64], cols 0-47 used)
    uint*   buk     = (uint*)(p + 25600000);            // 6.4 MB (own region)

    // merged: chunk histograms + packW2 + GEMM1 (one launch, co-scheduled, race-free)
    prepg_kernel<<<PREP_BLOCKS, 256, 0, stream>>>(W1, W2, Wb2, cnt2d, dst, x, ts1, N_NODES);
    scanB_kernel<<<1, 256, 0, stream>>>(cnt2d, bbase, cursorA, rowptr);
    partA_kernel<<<NCH, 256, 0, stream>>>(src, dst, cursorA, buk, N_EDGES);
    bucket_kernel<<<NBUK, 512, 0, stream>>>(buk, bbase, rowptr, dis, csr, N_NODES);

    // fused: gather64 (dis-folded) + relu/bias -> LDS -> GEMM2 -> ts2 (128 B rows)
    fused64_kernel<<<(N_NODES + 31) / 32, 256, 0, stream>>>(rowptr, csr, ts1, dis, b1, Wb2,
                                                            ts2, N_NODES);

    // layer 2 gather + log_softmax
    gather40ls_kernel<<<(N_NODES + 63) / 64, 320, 0, stream>>>(rowptr, csr, ts2, dis, b2,
                                                               out, N_NODES);
}

// Round 18
// 123.264 us; speedup vs baseline: 2.3617x; 1.1572x over previous
//
#include <hip/hip_runtime.h>

#define N_NODES 100000
#define N_EDGES 1600000
#define IN_DIM  128
#define HID_DIM 64
#define OUT_DIM 40

#define BUK_SHIFT 9
#define NBUK ((N_NODES + (1 << BUK_SHIFT) - 1) >> BUK_SHIFT)  // 196
#define CAP 12288                                             // edges per bucket slot (mean 8192, +45 sigma)
#define PART_CHUNK 4096
#define PART_EPT 16     // PART_CHUNK / 256
#define NCH ((N_EDGES + PART_CHUNK - 1) / PART_CHUNK)         // 391
#define MG_BLOCKS ((N_NODES + 127) / 128)                     // 782
#define PREP_BLOCKS (MG_BLOCKS + 3)                           // GEMM + 2 packW2 + cursor-init

typedef unsigned short ushort;
typedef unsigned int uint;
typedef __attribute__((ext_vector_type(8))) short bf16x8;
typedef __attribute__((ext_vector_type(4))) float f32x4;

// float -> bf16 bits, round-to-nearest-even
__device__ __forceinline__ ushort f2bf(float x) {
    uint u = __float_as_uint(x);
    uint r = ((u >> 16) & 1u) + 0x7fffu;
    return (ushort)((u + r) >> 16);
}

// ---------------- prepg: mgemm1 (blk 0..781) + packW2 (782..783) + cursorA init (784) -------
// mgemm1 stages W1 fragments in LDS per block (race-free); output UNSCALED XW1.
__global__ __launch_bounds__(256) void prepg_kernel(const float* __restrict__ W1,
                                                    const float* __restrict__ W2,
                                                    ushort* __restrict__ Wb2,
                                                    int* __restrict__ cursorA,
                                                    const float* __restrict__ X,
                                                    ushort* __restrict__ ts1, int M) {
    const int blk = blockIdx.x;
    const int t = threadIdx.x;
    if (blk < MG_BLOCKS) {
        __shared__ ushort wlds[16 * 64 * 8];   // 16 KB: frag f, lane l -> [(f*64+l)*8 + j]
        const int wave = t >> 6;
        const int lane = t & 63;
        const int la = lane & 15, lb = lane >> 4;

#pragma unroll
        for (int i = 0; i < 4; ++i) {
            int f = (t >> 6) + i * 4;         // 0..15
            int ks = f >> 2, ct = f & 3;
            int c = ct * 16 + la;
            int kb = ks * 32 + (lb << 3);
            ushort* wp = &wlds[(f * 64 + lane) * 8];
#pragma unroll
            for (int j = 0; j < 8; ++j)
                wp[j] = f2bf(W1[(kb + j) * HID_DIM + c]);
        }
        __syncthreads();

        const int r0 = blk * 128 + wave * 32;
        f32x4 acc[2][4];
#pragma unroll
        for (int i = 0; i < 2; ++i)
#pragma unroll
            for (int j = 0; j < 4; ++j)
#pragma unroll
                for (int r = 0; r < 4; ++r) acc[i][j][r] = 0.0f;

        int ra0 = r0 + la;       if (ra0 >= M) ra0 = M - 1;
        int ra1 = r0 + 16 + la;  if (ra1 >= M) ra1 = M - 1;
        const float* xp0 = X + (long long)ra0 * IN_DIM + lb * 8;
        const float* xp1 = X + (long long)ra1 * IN_DIM + lb * 8;
        const bf16x8* wb = (const bf16x8*)wlds;

#pragma unroll
        for (int ks = 0; ks < 4; ++ks) {
            float4 x00 = *(const float4*)(xp0 + ks * 32);
            float4 x01 = *(const float4*)(xp0 + ks * 32 + 4);
            float4 x10 = *(const float4*)(xp1 + ks * 32);
            float4 x11 = *(const float4*)(xp1 + ks * 32 + 4);
            bf16x8 a0, a1;
            a0[0] = (short)f2bf(x00.x); a0[1] = (short)f2bf(x00.y);
            a0[2] = (short)f2bf(x00.z); a0[3] = (short)f2bf(x00.w);
            a0[4] = (short)f2bf(x01.x); a0[5] = (short)f2bf(x01.y);
            a0[6] = (short)f2bf(x01.z); a0[7] = (short)f2bf(x01.w);
            a1[0] = (short)f2bf(x10.x); a1[1] = (short)f2bf(x10.y);
            a1[2] = (short)f2bf(x10.z); a1[3] = (short)f2bf(x10.w);
            a1[4] = (short)f2bf(x11.x); a1[5] = (short)f2bf(x11.y);
            a1[6] = (short)f2bf(x11.z); a1[7] = (short)f2bf(x11.w);
#pragma unroll
            for (int ct = 0; ct < 4; ++ct) {
                bf16x8 b = wb[(ks * 4 + ct) * 64 + lane];
                acc[0][ct] = __builtin_amdgcn_mfma_f32_16x16x32_bf16(a0, b, acc[0][ct], 0, 0, 0);
                acc[1][ct] = __builtin_amdgcn_mfma_f32_16x16x32_bf16(a1, b, acc[1][ct], 0, 0, 0);
            }
        }

#pragma unroll
        for (int rt = 0; rt < 2; ++rt)
#pragma unroll
            for (int r = 0; r < 4; ++r) {
                int row = r0 + rt * 16 + lb * 4 + r;
                if (row < M) {
#pragma unroll
                    for (int ct = 0; ct < 4; ++ct)
                        ts1[(long long)row * HID_DIM + ct * 16 + la] = f2bf(acc[rt][ct][r]);
                }
            }
    } else if (blk < MG_BLOCKS + 2) {
        int tt = (blk - MG_BLOCKS) * 256 + t;   // 0..511 (384 used): 2 ks * 3 ct * 64
        if (tt < 384) {
            int lane = tt & 63;
            int f = tt >> 6;          // 0..5
            int ks = f / 3, ct = f % 3;
            int c = ct * 16 + (lane & 15);
            int kb = ks * 32 + ((lane >> 4) << 3);
#pragma unroll
            for (int j = 0; j < 8; ++j)
                Wb2[tt * 8 + j] = (c < OUT_DIM) ? f2bf(W2[(kb + j) * OUT_DIM + c]) : 0;
        }
    } else {
        if (t < NBUK) cursorA[t] = t * CAP;    // fixed-capacity bucket bases
    }
}

// ---------------- pass A: partition edges into fixed-capacity dst-buckets (packed uint) -----
// entry = src | ((dst & 511) << 17)
__global__ __launch_bounds__(256) void partA_kernel(const int* __restrict__ src,
                                                    const int* __restrict__ dst,
                                                    int* __restrict__ cursorA,
                                                    uint* __restrict__ buk, int E) {
    __shared__ int hist[NBUK];
    __shared__ int base[NBUK];
    const int t = threadIdx.x;
    const int e0 = blockIdx.x * PART_CHUNK;
    for (int i = t; i < NBUK; i += 256) hist[i] = 0;
    __syncthreads();
    int mys[PART_EPT], myd[PART_EPT];
#pragma unroll
    for (int i = 0; i < PART_EPT; ++i) {
        int e = e0 + t + i * 256;
        if (e < E) {
            mys[i] = src[e];
            myd[i] = dst[e];
            atomicAdd(&hist[myd[i] >> BUK_SHIFT], 1);
        } else {
            myd[i] = -1;
        }
    }
    __syncthreads();
    for (int i = t; i < NBUK; i += 256)
        base[i] = (hist[i] > 0) ? atomicAdd(&cursorA[i], hist[i]) : 0;
    __syncthreads();
    for (int i = t; i < NBUK; i += 256) hist[i] = 0;
    __syncthreads();
#pragma unroll
    for (int i = 0; i < PART_EPT; ++i) {
        if (myd[i] >= 0) {
            int b = myd[i] >> BUK_SHIFT;
            int pos = base[b] + atomicAdd(&hist[b], 1);
            buk[pos] = (uint)mys[i] | ((uint)(myd[i] & 511) << 17);
        }
    }
}

// ---------------- per-bucket: degrees + rowbeg/rowend + dis + csr fill, all LDS -------------
// beg = b*CAP (static), end = cursorA[b] (post-partA).
__global__ __launch_bounds__(512) void bucket_kernel(const uint* __restrict__ buk,
                                                     const int* __restrict__ cursorA,
                                                     int* __restrict__ rowbeg,
                                                     int* __restrict__ rowend,
                                                     float* __restrict__ dis,
                                                     int* __restrict__ csr, int n) {
    __shared__ int cnt[512];
    __shared__ int pre[512];
    const int t = threadIdx.x;
    const int b = blockIdx.x;
    const int beg = b * CAP, end = cursorA[b];
    cnt[t] = 0;
    __syncthreads();
    for (int i = beg + t; i < end; i += 512)
        atomicAdd(&cnt[(buk[i] >> 17) & 511], 1);
    __syncthreads();
    const int c = cnt[t];
    pre[t] = c;
    __syncthreads();
    for (int off = 1; off < 512; off <<= 1) {
        int v = (t >= off) ? pre[t - off] : 0;
        __syncthreads();
        pre[t] += v;
        __syncthreads();
    }
    const int ex = pre[t] - c;
    const int v0 = (b << BUK_SHIFT) + t;
    if (v0 < n) {
        rowbeg[v0] = beg + ex;
        rowend[v0] = beg + ex + c;
        dis[v0] = rsqrtf((float)c + 1.0f);
    }
    __syncthreads();
    cnt[t] = beg + ex;
    __syncthreads();
    for (int i = beg + t; i < end; i += 512) {
        uint e = buk[i];
        int pos = atomicAdd(&cnt[(e >> 17) & 511], 1);
        csr[pos] = (int)(e & 0x1FFFFu);
    }
}

// ---------------- bf16 unpack helpers ----------------
__device__ __forceinline__ void add_bf8(float* acc, uint4 m) {
    acc[0] += __uint_as_float(m.x << 16);
    acc[1] += __uint_as_float(m.x & 0xffff0000u);
    acc[2] += __uint_as_float(m.y << 16);
    acc[3] += __uint_as_float(m.y & 0xffff0000u);
    acc[4] += __uint_as_float(m.z << 16);
    acc[5] += __uint_as_float(m.z & 0xffff0000u);
    acc[6] += __uint_as_float(m.w << 16);
    acc[7] += __uint_as_float(m.w & 0xffff0000u);
}

__device__ __forceinline__ void init_bf8(float* acc, uint4 m) {
    acc[0] = __uint_as_float(m.x << 16);
    acc[1] = __uint_as_float(m.x & 0xffff0000u);
    acc[2] = __uint_as_float(m.y << 16);
    acc[3] = __uint_as_float(m.y & 0xffff0000u);
    acc[4] = __uint_as_float(m.z << 16);
    acc[5] = __uint_as_float(m.z & 0xffff0000u);
    acc[6] = __uint_as_float(m.w << 16);
    acc[7] = __uint_as_float(m.w & 0xffff0000u);
}

// acc += s * unpack(m)
__device__ __forceinline__ void fma_bf8(float* acc, uint4 m, float s) {
    acc[0] = fmaf(s, __uint_as_float(m.x << 16), acc[0]);
    acc[1] = fmaf(s, __uint_as_float(m.x & 0xffff0000u), acc[1]);
    acc[2] = fmaf(s, __uint_as_float(m.y << 16), acc[2]);
    acc[3] = fmaf(s, __uint_as_float(m.y & 0xffff0000u), acc[3]);
    acc[4] = fmaf(s, __uint_as_float(m.z << 16), acc[4]);
    acc[5] = fmaf(s, __uint_as_float(m.z & 0xffff0000u), acc[5]);
    acc[6] = fmaf(s, __uint_as_float(m.w << 16), acc[6]);
    acc[7] = fmaf(s, __uint_as_float(m.w & 0xffff0000u), acc[7]);
}

// 4-deep pipelined neighbor accumulation (unscaled); STRIDE = row stride in uint4
template<int STRIDE>
__device__ __forceinline__ void gather_pipe4(const uint4* __restrict__ tsv,
                                             const int* __restrict__ csr,
                                             int beg, int end, int q, float* acc) {
    int j = beg;
    if (j + 3 < end) {
        int c0 = csr[j], c1 = csr[j + 1], c2 = csr[j + 2], c3 = csr[j + 3];
        j += 4;
        for (; j + 3 < end; j += 4) {
            int n0 = csr[j], n1 = csr[j + 1], n2 = csr[j + 2], n3 = csr[j + 3];
            uint4 m0 = tsv[c0 * STRIDE + q];
            uint4 m1 = tsv[c1 * STRIDE + q];
            uint4 m2 = tsv[c2 * STRIDE + q];
            uint4 m3 = tsv[c3 * STRIDE + q];
            add_bf8(acc, m0); add_bf8(acc, m1); add_bf8(acc, m2); add_bf8(acc, m3);
            c0 = n0; c1 = n1; c2 = n2; c3 = n3;
        }
        uint4 m0 = tsv[c0 * STRIDE + q];
        uint4 m1 = tsv[c1 * STRIDE + q];
        uint4 m2 = tsv[c2 * STRIDE + q];
        uint4 m3 = tsv[c3 * STRIDE + q];
        add_bf8(acc, m0); add_bf8(acc, m1); add_bf8(acc, m2); add_bf8(acc, m3);
    }
    for (; j < end; ++j) add_bf8(acc, tsv[csr[j] * STRIDE + q]);
}

// 4-deep pipelined neighbor accumulation with per-neighbor dis scale
template<int STRIDE>
__device__ __forceinline__ void gather_pipe4s(const uint4* __restrict__ tsv,
                                              const int* __restrict__ csr,
                                              const float* __restrict__ dis,
                                              int beg, int end, int q, float* acc) {
    int j = beg;
    if (j + 3 < end) {
        int c0 = csr[j], c1 = csr[j + 1], c2 = csr[j + 2], c3 = csr[j + 3];
        j += 4;
        for (; j + 3 < end; j += 4) {
            int n0 = csr[j], n1 = csr[j + 1], n2 = csr[j + 2], n3 = csr[j + 3];
            float d0 = dis[c0], d1 = dis[c1], d2 = dis[c2], d3 = dis[c3];
            uint4 m0 = tsv[c0 * STRIDE + q];
            uint4 m1 = tsv[c1 * STRIDE + q];
            uint4 m2 = tsv[c2 * STRIDE + q];
            uint4 m3 = tsv[c3 * STRIDE + q];
            fma_bf8(acc, m0, d0); fma_bf8(acc, m1, d1);
            fma_bf8(acc, m2, d2); fma_bf8(acc, m3, d3);
            c0 = n0; c1 = n1; c2 = n2; c3 = n3;
        }
        float d0 = dis[c0], d1 = dis[c1], d2 = dis[c2], d3 = dis[c3];
        uint4 m0 = tsv[c0 * STRIDE + q];
        uint4 m1 = tsv[c1 * STRIDE + q];
        uint4 m2 = tsv[c2 * STRIDE + q];
        uint4 m3 = tsv[c3 * STRIDE + q];
        fma_bf8(acc, m0, d0); fma_bf8(acc, m1, d1);
        fma_bf8(acc, m2, d2); fma_bf8(acc, m3, d3);
    }
    for (; j < end; ++j) { int u = csr[j]; fma_bf8(acc, tsv[u * STRIDE + q], dis[u]); }
}

// ---------------- fused: gather64 (dis[u]-scaled, 8 thr/node) -> LDS h -> MFMA GEMM2 --------
// ts1 is UNSCALED XW1; gather applies dis[u] per neighbor, dis[v] in epilogue.
// ts2 rows padded to 64 bf16 (128 B); cols 0-47 written, 0-39 read later.
__global__ __launch_bounds__(256) void fused64_kernel(const int* __restrict__ rowbeg,
                                                      const int* __restrict__ rowend,
                                                      const int* __restrict__ csr,
                                                      const ushort* __restrict__ ts,
                                                      const float* __restrict__ dis,
                                                      const float* __restrict__ b1,
                                                      const ushort* __restrict__ Wb2,
                                                      ushort* __restrict__ Y, int n) {
    __shared__ ushort hs[32][72];   // 144 B row stride
    const int t = threadIdx.x;
    const int vloc = t >> 3, q = t & 7;
    const int v = blockIdx.x * 32 + vloc;

    if (v < n) {
        const uint4* tsv = (const uint4*)ts;
        int beg = rowbeg[v], end = rowend[v];
        float dv = dis[v];
        float acc[8] = {0.f, 0.f, 0.f, 0.f, 0.f, 0.f, 0.f, 0.f};
        fma_bf8(acc, tsv[(long long)v * 8 + q], dv);   // self-loop: dis[v]*ts1[v]
        gather_pipe4s<8>(tsv, csr, dis, beg, end, q, acc);

        float4 b0 = ((const float4*)b1)[q * 2];
        float4 bb = ((const float4*)b1)[q * 2 + 1];
        float r0 = fmaxf(acc[0] * dv + b0.x, 0.0f);
        float r1 = fmaxf(acc[1] * dv + b0.y, 0.0f);
        float r2 = fmaxf(acc[2] * dv + b0.z, 0.0f);
        float r3 = fmaxf(acc[3] * dv + b0.w, 0.0f);
        float r4 = fmaxf(acc[4] * dv + bb.x, 0.0f);
        float r5 = fmaxf(acc[5] * dv + bb.y, 0.0f);
        float r6 = fmaxf(acc[6] * dv + bb.z, 0.0f);
        float r7 = fmaxf(acc[7] * dv + bb.w, 0.0f);
        uint4 o;
        o.x = ((uint)f2bf(r1) << 16) | f2bf(r0);
        o.y = ((uint)f2bf(r3) << 16) | f2bf(r2);
        o.z = ((uint)f2bf(r5) << 16) | f2bf(r4);
        o.w = ((uint)f2bf(r7) << 16) | f2bf(r6);
        *(uint4*)&hs[vloc][q * 8] = o;
    } else {
        uint4 z = {0u, 0u, 0u, 0u};
        *(uint4*)&hs[vloc][q * 8] = z;
    }
    __syncthreads();

    if (t < 128) {
        const int wave = t >> 6;           // 0 or 1 -> 16-node tile
        const int lane = t & 63;
        const int la = lane & 15, fg = lane >> 4;
        bf16x8 a0 = *(const bf16x8*)&hs[wave * 16 + la][fg * 8];
        bf16x8 a1 = *(const bf16x8*)&hs[wave * 16 + la][32 + fg * 8];

        const bf16x8* wb = (const bf16x8*)Wb2;
        f32x4 dacc[3];
#pragma unroll
        for (int ct = 0; ct < 3; ++ct)
#pragma unroll
            for (int r = 0; r < 4; ++r) dacc[ct][r] = 0.0f;
#pragma unroll
        for (int ct = 0; ct < 3; ++ct) {
            dacc[ct] = __builtin_amdgcn_mfma_f32_16x16x32_bf16(a0, wb[ct * 64 + lane], dacc[ct], 0, 0, 0);
            dacc[ct] = __builtin_amdgcn_mfma_f32_16x16x32_bf16(a1, wb[(3 + ct) * 64 + lane], dacc[ct], 0, 0, 0);
        }

        const int rbase = blockIdx.x * 32 + wave * 16 + fg * 4;
#pragma unroll
        for (int r = 0; r < 4; ++r) {
            int row = rbase + r;
            if (row < n) {
                float dvr = dis[row];
#pragma unroll
                for (int ct = 0; ct < 3; ++ct)
                    Y[(long long)row * 64 + ct * 16 + la] = f2bf(dacc[ct][r] * dvr);
            }
        }
    }
}

// ---------------- fused gather 40 + log_softmax: block=320 (64 nodes), 4-deep pipeline --------
// ts rows are 64 bf16 (8 uint4) stride; q in [0,5) covers exactly the 40 real cols.
__global__ __launch_bounds__(320) void gather40ls_kernel(const int* __restrict__ rowbeg,
                                                         const int* __restrict__ rowend,
                                                         const int* __restrict__ csr,
                                                         const ushort* __restrict__ ts,
                                                         const float* __restrict__ dis,
                                                         const float* __restrict__ b,
                                                         float* __restrict__ out, int n) {
    __shared__ float smax[64][5];
    __shared__ float ssum[64][5];
    const int t = threadIdx.x;
    const int vloc = t / 5, q = t - vloc * 5;
    const int v = blockIdx.x * 64 + vloc;
    const bool active = (v < n);

    float r[8];
    if (active) {
        const uint4* tsv = (const uint4*)ts;   // row stride 64 bf16 = 8 uint4
        int beg = rowbeg[v], end = rowend[v];
        float acc[8];
        init_bf8(acc, tsv[(long long)v * 8 + q]);
        gather_pipe4<8>(tsv, csr, beg, end, q, acc);

        float dv = dis[v];
        float4 b0 = ((const float4*)b)[q * 2];
        float4 b1 = ((const float4*)b)[q * 2 + 1];
        r[0] = acc[0] * dv + b0.x;
        r[1] = acc[1] * dv + b0.y;
        r[2] = acc[2] * dv + b0.z;
        r[3] = acc[3] * dv + b0.w;
        r[4] = acc[4] * dv + b1.x;
        r[5] = acc[5] * dv + b1.y;
        r[6] = acc[6] * dv + b1.z;
        r[7] = acc[7] * dv + b1.w;
    } else {
#pragma unroll
        for (int i = 0; i < 8; ++i) r[i] = 0.0f;
    }

    float m = r[0];
#pragma unroll
    for (int i = 1; i < 8; ++i) m = fmaxf(m, r[i]);
    smax[vloc][q] = m;
    __syncthreads();
    float gm = fmaxf(fmaxf(fmaxf(smax[vloc][0], smax[vloc][1]), fmaxf(smax[vloc][2], smax[vloc][3])),
                     smax[vloc][4]);
    float s = 0.0f;
#pragma unroll
    for (int i = 0; i < 8; ++i) s += __expf(r[i] - gm);
    ssum[vloc][q] = s;
    __syncthreads();
    float tot = ssum[vloc][0] + ssum[vloc][1] + ssum[vloc][2] + ssum[vloc][3] + ssum[vloc][4];
    float c = gm + __logf(tot);

    if (active) {
        float* rp = out + (long long)v * OUT_DIM + q * 8;
        float4 o0 = { r[0] - c, r[1] - c, r[2] - c, r[3] - c };
        float4 o1 = { r[4] - c, r[5] - c, r[6] - c, r[7] - c };
        ((float4*)rp)[0] = o0;
        ((float4*)rp)[1] = o1;
    }
}

extern "C" void kernel_launch(void* const* d_in, const int* in_sizes, int n_in,
                              void* d_out, int out_size, void* d_ws, size_t ws_size,
                              hipStream_t stream) {
    const float* x  = (const float*)d_in[0];
    const int*   ei = (const int*)d_in[1];
    const float* W1 = (const float*)d_in[2];
    const float* b1 = (const float*)d_in[3];
    const float* W2 = (const float*)d_in[4];
    const float* b2 = (const float*)d_in[5];
    float* out = (float*)d_out;

    const int* src = ei;
    const int* dst = ei + N_EDGES;

    // workspace layout (bytes) — non-overlapping; csr/buk are CAP-padded (196*12288*4 = 9.63 MB)
    char* ws = (char*)d_ws;
    int*    rowbeg  = (int*)ws;                         // [0, 400K)
    int*    rowend  = (int*)(ws + (512 << 10));         // [512K, +400K)
    float*  dis     = (float*)(ws + (1024 << 10));      // [1024K, +400K)
    int*    cursorA = (int*)(ws + (1536 << 10));        // 784 B
    ushort* Wb2     = (ushort*)(ws + (1540 << 10));     // 6 KB
    int*    csr     = (int*)(ws + (2048 << 10));        // 9.63 MB -> ends ~11.7 MB
    char*   p       = ws + (12288 << 10);               // 12 MB
    ushort* ts1     = (ushort*)p;                       // 12.8 MB (bf16 [M][64], unscaled XW1)
    ushort* ts2     = (ushort*)(p + 12800000);          // 12.8 MB (bf16 [M][64], cols 0-47 used)
    uint*   buk     = (uint*)(p + 25600000);            // 9.63 MB

    // prepg: GEMM1 + packW2 + bucket-cursor init (one launch, race-free)
    prepg_kernel<<<PREP_BLOCKS, 256, 0, stream>>>(W1, W2, Wb2, cursorA, x, ts1, N_NODES);

    // fixed-capacity bucket partition, then per-bucket CSR build
    partA_kernel<<<NCH, 256, 0, stream>>>(src, dst, cursorA, buk, N_EDGES);
    bucket_kernel<<<NBUK, 512, 0, stream>>>(buk, cursorA, rowbeg, rowend, dis, csr, N_NODES);

    // fused: gather64 (dis-folded) + relu/bias -> LDS -> GEMM2 -> ts2 (128 B rows)
    fused64_kernel<<<(N_NODES + 31) / 32, 256, 0, stream>>>(rowbeg, rowend, csr, ts1, dis, b1,
                                                            Wb2, ts2, N_NODES);

    // layer 2 gather + log_softmax
    gather40ls_kernel<<<(N_NODES + 63) / 64, 320, 0, stream>>>(rowbeg, rowend, csr, ts2, dis,
                                                               b2, out, N_NODES);
}

// Round 19
// 119.509 us; speedup vs baseline: 2.4359x; 1.0314x over previous
//
#include <hip/hip_runtime.h>

#define N_NODES 100000
#define N_EDGES 1600000
#define IN_DIM  128
#define HID_DIM 64
#define OUT_DIM 40

#define BUK_SHIFT 9
#define NBUK ((N_NODES + (1 << BUK_SHIFT) - 1) >> BUK_SHIFT)  // 196
#define CAP 12288                                             // edges per bucket slot
#define PART_CHUNK 4096
#define PART_EPT 16     // PART_CHUNK / 256
#define NCH ((N_EDGES + PART_CHUNK - 1) / PART_CHUNK)         // 391
#define MG_BLOCKS ((N_NODES + 127) / 128)                     // 782
#define MERGE_BLOCKS (NCH + MG_BLOCKS + 2)                    // partA + GEMM1 + packW2

typedef unsigned short ushort;
typedef unsigned int uint;
typedef __attribute__((ext_vector_type(8))) short bf16x8;
typedef __attribute__((ext_vector_type(4))) float f32x4;

// float -> bf16 bits, round-to-nearest-even
__device__ __forceinline__ ushort f2bf(float x) {
    uint u = __float_as_uint(x);
    uint r = ((u >> 16) & 1u) + 0x7fffu;
    return (ushort)((u + r) >> 16);
}

// ---------------- merged: partA (blk 0..390) + mgemm1 (391..1172) + packW2 (1173..1174) ----
// All three branches are mutually independent (no intra-launch producer/consumer).
// partA uses RELATIVE bucket cursors (cursorA zero-initialized by hipMemsetAsync).
__global__ __launch_bounds__(256) void merged_kernel(const int* __restrict__ src,
                                                     const int* __restrict__ dst,
                                                     int* __restrict__ cursorA,
                                                     uint* __restrict__ buk,
                                                     const float* __restrict__ W1,
                                                     const float* __restrict__ W2,
                                                     ushort* __restrict__ Wb2,
                                                     const float* __restrict__ X,
                                                     ushort* __restrict__ ts1, int M) {
    const int blk = blockIdx.x;
    const int t = threadIdx.x;
    if (blk < NCH) {
        // ---- partA: partition edges into fixed-capacity dst-buckets (packed uint) ----
        __shared__ int hist[NBUK];
        __shared__ int base[NBUK];
        const int e0 = blk * PART_CHUNK;
        for (int i = t; i < NBUK; i += 256) hist[i] = 0;
        __syncthreads();
        int mys[PART_EPT], myd[PART_EPT];
#pragma unroll
        for (int i = 0; i < PART_EPT; ++i) {
            int e = e0 + t + i * 256;
            if (e < N_EDGES) {
                mys[i] = src[e];
                myd[i] = dst[e];
                atomicAdd(&hist[myd[i] >> BUK_SHIFT], 1);
            } else {
                myd[i] = -1;
            }
        }
        __syncthreads();
        for (int i = t; i < NBUK; i += 256)
            base[i] = (hist[i] > 0) ? atomicAdd(&cursorA[i], hist[i]) : 0;
        __syncthreads();
        for (int i = t; i < NBUK; i += 256) hist[i] = 0;
        __syncthreads();
#pragma unroll
        for (int i = 0; i < PART_EPT; ++i) {
            if (myd[i] >= 0) {
                int b = myd[i] >> BUK_SHIFT;
                int pos = b * CAP + base[b] + atomicAdd(&hist[b], 1);
                buk[pos] = (uint)mys[i] | ((uint)(myd[i] & 511) << 17);
            }
        }
    } else if (blk < NCH + MG_BLOCKS) {
        // ---- mgemm1: ts1 = X @ W1 (bf16, UNSCALED; dis applied in fused64) ----
        __shared__ ushort wlds[16 * 64 * 8];   // 16 KB
        const int gblk = blk - NCH;
        const int wave = t >> 6;
        const int lane = t & 63;
        const int la = lane & 15, lb = lane >> 4;

#pragma unroll
        for (int i = 0; i < 4; ++i) {
            int f = (t >> 6) + i * 4;         // 0..15
            int ks = f >> 2, ct = f & 3;
            int c = ct * 16 + la;
            int kb = ks * 32 + (lb << 3);
            ushort* wp = &wlds[(f * 64 + lane) * 8];
#pragma unroll
            for (int j = 0; j < 8; ++j)
                wp[j] = f2bf(W1[(kb + j) * HID_DIM + c]);
        }
        __syncthreads();

        const int r0 = gblk * 128 + wave * 32;
        f32x4 acc[2][4];
#pragma unroll
        for (int i = 0; i < 2; ++i)
#pragma unroll
            for (int j = 0; j < 4; ++j)
#pragma unroll
                for (int r = 0; r < 4; ++r) acc[i][j][r] = 0.0f;

        int ra0 = r0 + la;       if (ra0 >= M) ra0 = M - 1;
        int ra1 = r0 + 16 + la;  if (ra1 >= M) ra1 = M - 1;
        const float* xp0 = X + (long long)ra0 * IN_DIM + lb * 8;
        const float* xp1 = X + (long long)ra1 * IN_DIM + lb * 8;
        const bf16x8* wb = (const bf16x8*)wlds;

#pragma unroll
        for (int ks = 0; ks < 4; ++ks) {
            float4 x00 = *(const float4*)(xp0 + ks * 32);
            float4 x01 = *(const float4*)(xp0 + ks * 32 + 4);
            float4 x10 = *(const float4*)(xp1 + ks * 32);
            float4 x11 = *(const float4*)(xp1 + ks * 32 + 4);
            bf16x8 a0, a1;
            a0[0] = (short)f2bf(x00.x); a0[1] = (short)f2bf(x00.y);
            a0[2] = (short)f2bf(x00.z); a0[3] = (short)f2bf(x00.w);
            a0[4] = (short)f2bf(x01.x); a0[5] = (short)f2bf(x01.y);
            a0[6] = (short)f2bf(x01.z); a0[7] = (short)f2bf(x01.w);
            a1[0] = (short)f2bf(x10.x); a1[1] = (short)f2bf(x10.y);
            a1[2] = (short)f2bf(x10.z); a1[3] = (short)f2bf(x10.w);
            a1[4] = (short)f2bf(x11.x); a1[5] = (short)f2bf(x11.y);
            a1[6] = (short)f2bf(x11.z); a1[7] = (short)f2bf(x11.w);
#pragma unroll
            for (int ct = 0; ct < 4; ++ct) {
                bf16x8 b = wb[(ks * 4 + ct) * 64 + lane];
                acc[0][ct] = __builtin_amdgcn_mfma_f32_16x16x32_bf16(a0, b, acc[0][ct], 0, 0, 0);
                acc[1][ct] = __builtin_amdgcn_mfma_f32_16x16x32_bf16(a1, b, acc[1][ct], 0, 0, 0);
            }
        }

#pragma unroll
        for (int rt = 0; rt < 2; ++rt)
#pragma unroll
            for (int r = 0; r < 4; ++r) {
                int row = r0 + rt * 16 + lb * 4 + r;
                if (row < M) {
#pragma unroll
                    for (int ct = 0; ct < 4; ++ct)
                        ts1[(long long)row * HID_DIM + ct * 16 + la] = f2bf(acc[rt][ct][r]);
                }
            }
    } else {
        // ---- packW2 ----
        int tt = (blk - NCH - MG_BLOCKS) * 256 + t;   // 0..511 (384 used)
        if (tt < 384) {
            int lane = tt & 63;
            int f = tt >> 6;          // 0..5
            int ks = f / 3, ct = f % 3;
            int c = ct * 16 + (lane & 15);
            int kb = ks * 32 + ((lane >> 4) << 3);
#pragma unroll
            for (int j = 0; j < 8; ++j)
                Wb2[tt * 8 + j] = (c < OUT_DIM) ? f2bf(W2[(kb + j) * OUT_DIM + c]) : 0;
        }
    }
}

// ---------------- per-bucket: degrees + rowbeg/rowend + dis + csr fill, all LDS -------------
// beg = b*CAP (static), end = b*CAP + cursorA[b] (relative count post-partA).
__global__ __launch_bounds__(512) void bucket_kernel(const uint* __restrict__ buk,
                                                     const int* __restrict__ cursorA,
                                                     int* __restrict__ rowbeg,
                                                     int* __restrict__ rowend,
                                                     float* __restrict__ dis,
                                                     int* __restrict__ csr, int n) {
    __shared__ int cnt[512];
    __shared__ int pre[512];
    const int t = threadIdx.x;
    const int b = blockIdx.x;
    const int beg = b * CAP, end = b * CAP + cursorA[b];
    cnt[t] = 0;
    __syncthreads();
    for (int i = beg + t; i < end; i += 512)
        atomicAdd(&cnt[(buk[i] >> 17) & 511], 1);
    __syncthreads();
    const int c = cnt[t];
    pre[t] = c;
    __syncthreads();
    for (int off = 1; off < 512; off <<= 1) {
        int v = (t >= off) ? pre[t - off] : 0;
        __syncthreads();
        pre[t] += v;
        __syncthreads();
    }
    const int ex = pre[t] - c;
    const int v0 = (b << BUK_SHIFT) + t;
    if (v0 < n) {
        rowbeg[v0] = beg + ex;
        rowend[v0] = beg + ex + c;
        dis[v0] = rsqrtf((float)c + 1.0f);
    }
    __syncthreads();
    cnt[t] = beg + ex;
    __syncthreads();
    for (int i = beg + t; i < end; i += 512) {
        uint e = buk[i];
        int pos = atomicAdd(&cnt[(e >> 17) & 511], 1);
        csr[pos] = (int)(e & 0x1FFFFu);
    }
}

// ---------------- bf16 unpack helpers ----------------
__device__ __forceinline__ void add_bf8(float* acc, uint4 m) {
    acc[0] += __uint_as_float(m.x << 16);
    acc[1] += __uint_as_float(m.x & 0xffff0000u);
    acc[2] += __uint_as_float(m.y << 16);
    acc[3] += __uint_as_float(m.y & 0xffff0000u);
    acc[4] += __uint_as_float(m.z << 16);
    acc[5] += __uint_as_float(m.z & 0xffff0000u);
    acc[6] += __uint_as_float(m.w << 16);
    acc[7] += __uint_as_float(m.w & 0xffff0000u);
}

__device__ __forceinline__ void init_bf8(float* acc, uint4 m) {
    acc[0] = __uint_as_float(m.x << 16);
    acc[1] = __uint_as_float(m.x & 0xffff0000u);
    acc[2] = __uint_as_float(m.y << 16);
    acc[3] = __uint_as_float(m.y & 0xffff0000u);
    acc[4] = __uint_as_float(m.z << 16);
    acc[5] = __uint_as_float(m.z & 0xffff0000u);
    acc[6] = __uint_as_float(m.w << 16);
    acc[7] = __uint_as_float(m.w & 0xffff0000u);
}

// acc += s * unpack(m)
__device__ __forceinline__ void fma_bf8(float* acc, uint4 m, float s) {
    acc[0] = fmaf(s, __uint_as_float(m.x << 16), acc[0]);
    acc[1] = fmaf(s, __uint_as_float(m.x & 0xffff0000u), acc[1]);
    acc[2] = fmaf(s, __uint_as_float(m.y << 16), acc[2]);
    acc[3] = fmaf(s, __uint_as_float(m.y & 0xffff0000u), acc[3]);
    acc[4] = fmaf(s, __uint_as_float(m.z << 16), acc[4]);
    acc[5] = fmaf(s, __uint_as_float(m.z & 0xffff0000u), acc[5]);
    acc[6] = fmaf(s, __uint_as_float(m.w << 16), acc[6]);
    acc[7] = fmaf(s, __uint_as_float(m.w & 0xffff0000u), acc[7]);
}

// 4-deep pipelined neighbor accumulation (unscaled); STRIDE = row stride in uint4
template<int STRIDE>
__device__ __forceinline__ void gather_pipe4(const uint4* __restrict__ tsv,
                                             const int* __restrict__ csr,
                                             int beg, int end, int q, float* acc) {
    int j = beg;
    if (j + 3 < end) {
        int c0 = csr[j], c1 = csr[j + 1], c2 = csr[j + 2], c3 = csr[j + 3];
        j += 4;
        for (; j + 3 < end; j += 4) {
            int n0 = csr[j], n1 = csr[j + 1], n2 = csr[j + 2], n3 = csr[j + 3];
            uint4 m0 = tsv[c0 * STRIDE + q];
            uint4 m1 = tsv[c1 * STRIDE + q];
            uint4 m2 = tsv[c2 * STRIDE + q];
            uint4 m3 = tsv[c3 * STRIDE + q];
            add_bf8(acc, m0); add_bf8(acc, m1); add_bf8(acc, m2); add_bf8(acc, m3);
            c0 = n0; c1 = n1; c2 = n2; c3 = n3;
        }
        uint4 m0 = tsv[c0 * STRIDE + q];
        uint4 m1 = tsv[c1 * STRIDE + q];
        uint4 m2 = tsv[c2 * STRIDE + q];
        uint4 m3 = tsv[c3 * STRIDE + q];
        add_bf8(acc, m0); add_bf8(acc, m1); add_bf8(acc, m2); add_bf8(acc, m3);
    }
    for (; j < end; ++j) add_bf8(acc, tsv[csr[j] * STRIDE + q]);
}

// 4-deep pipelined neighbor accumulation with per-neighbor dis scale
template<int STRIDE>
__device__ __forceinline__ void gather_pipe4s(const uint4* __restrict__ tsv,
                                              const int* __restrict__ csr,
                                              const float* __restrict__ dis,
                                              int beg, int end, int q, float* acc) {
    int j = beg;
    if (j + 3 < end) {
        int c0 = csr[j], c1 = csr[j + 1], c2 = csr[j + 2], c3 = csr[j + 3];
        j += 4;
        for (; j + 3 < end; j += 4) {
            int n0 = csr[j], n1 = csr[j + 1], n2 = csr[j + 2], n3 = csr[j + 3];
            float d0 = dis[c0], d1 = dis[c1], d2 = dis[c2], d3 = dis[c3];
            uint4 m0 = tsv[c0 * STRIDE + q];
            uint4 m1 = tsv[c1 * STRIDE + q];
            uint4 m2 = tsv[c2 * STRIDE + q];
            uint4 m3 = tsv[c3 * STRIDE + q];
            fma_bf8(acc, m0, d0); fma_bf8(acc, m1, d1);
            fma_bf8(acc, m2, d2); fma_bf8(acc, m3, d3);
            c0 = n0; c1 = n1; c2 = n2; c3 = n3;
        }
        float d0 = dis[c0], d1 = dis[c1], d2 = dis[c2], d3 = dis[c3];
        uint4 m0 = tsv[c0 * STRIDE + q];
        uint4 m1 = tsv[c1 * STRIDE + q];
        uint4 m2 = tsv[c2 * STRIDE + q];
        uint4 m3 = tsv[c3 * STRIDE + q];
        fma_bf8(acc, m0, d0); fma_bf8(acc, m1, d1);
        fma_bf8(acc, m2, d2); fma_bf8(acc, m3, d3);
    }
    for (; j < end; ++j) { int u = csr[j]; fma_bf8(acc, tsv[u * STRIDE + q], dis[u]); }
}

// ---------------- fused: gather64 (dis[u]-scaled, 8 thr/node) -> LDS h -> MFMA GEMM2 --------
__global__ __launch_bounds__(256) void fused64_kernel(const int* __restrict__ rowbeg,
                                                      const int* __restrict__ rowend,
                                                      const int* __restrict__ csr,
                                                      const ushort* __restrict__ ts,
                                                      const float* __restrict__ dis,
                                                      const float* __restrict__ b1,
                                                      const ushort* __restrict__ Wb2,
                                                      ushort* __restrict__ Y, int n) {
    __shared__ ushort hs[32][72];   // 144 B row stride
    const int t = threadIdx.x;
    const int vloc = t >> 3, q = t & 7;
    const int v = blockIdx.x * 32 + vloc;

    if (v < n) {
        const uint4* tsv = (const uint4*)ts;
        int beg = rowbeg[v], end = rowend[v];
        float dv = dis[v];
        float acc[8] = {0.f, 0.f, 0.f, 0.f, 0.f, 0.f, 0.f, 0.f};
        fma_bf8(acc, tsv[(long long)v * 8 + q], dv);   // self-loop: dis[v]*ts1[v]
        gather_pipe4s<8>(tsv, csr, dis, beg, end, q, acc);

        float4 b0 = ((const float4*)b1)[q * 2];
        float4 bb = ((const float4*)b1)[q * 2 + 1];
        float r0 = fmaxf(acc[0] * dv + b0.x, 0.0f);
        float r1 = fmaxf(acc[1] * dv + b0.y, 0.0f);
        float r2 = fmaxf(acc[2] * dv + b0.z, 0.0f);
        float r3 = fmaxf(acc[3] * dv + b0.w, 0.0f);
        float r4 = fmaxf(acc[4] * dv + bb.x, 0.0f);
        float r5 = fmaxf(acc[5] * dv + bb.y, 0.0f);
        float r6 = fmaxf(acc[6] * dv + bb.z, 0.0f);
        float r7 = fmaxf(acc[7] * dv + bb.w, 0.0f);
        uint4 o;
        o.x = ((uint)f2bf(r1) << 16) | f2bf(r0);
        o.y = ((uint)f2bf(r3) << 16) | f2bf(r2);
        o.z = ((uint)f2bf(r5) << 16) | f2bf(r4);
        o.w = ((uint)f2bf(r7) << 16) | f2bf(r6);
        *(uint4*)&hs[vloc][q * 8] = o;
    } else {
        uint4 z = {0u, 0u, 0u, 0u};
        *(uint4*)&hs[vloc][q * 8] = z;
    }
    __syncthreads();

    if (t < 128) {
        const int wave = t >> 6;           // 0 or 1 -> 16-node tile
        const int lane = t & 63;
        const int la = lane & 15, fg = lane >> 4;
        bf16x8 a0 = *(const bf16x8*)&hs[wave * 16 + la][fg * 8];
        bf16x8 a1 = *(const bf16x8*)&hs[wave * 16 + la][32 + fg * 8];

        const bf16x8* wb = (const bf16x8*)Wb2;
        f32x4 dacc[3];
#pragma unroll
        for (int ct = 0; ct < 3; ++ct)
#pragma unroll
            for (int r = 0; r < 4; ++r) dacc[ct][r] = 0.0f;
#pragma unroll
        for (int ct = 0; ct < 3; ++ct) {
            dacc[ct] = __builtin_amdgcn_mfma_f32_16x16x32_bf16(a0, wb[ct * 64 + lane], dacc[ct], 0, 0, 0);
            dacc[ct] = __builtin_amdgcn_mfma_f32_16x16x32_bf16(a1, wb[(3 + ct) * 64 + lane], dacc[ct], 0, 0, 0);
        }

        const int rbase = blockIdx.x * 32 + wave * 16 + fg * 4;
#pragma unroll
        for (int r = 0; r < 4; ++r) {
            int row = rbase + r;
            if (row < n) {
                float dvr = dis[row];
#pragma unroll
                for (int ct = 0; ct < 3; ++ct)
                    Y[(long long)row * 64 + ct * 16 + la] = f2bf(dacc[ct][r] * dvr);
            }
        }
    }
}

// ---------------- fused gather 40 + log_softmax: block=320 (64 nodes), 4-deep pipeline --------
__global__ __launch_bounds__(320) void gather40ls_kernel(const int* __restrict__ rowbeg,
                                                         const int* __restrict__ rowend,
                                                         const int* __restrict__ csr,
                                                         const ushort* __restrict__ ts,
                                                         const float* __restrict__ dis,
                                                         const float* __restrict__ b,
                                                         float* __restrict__ out, int n) {
    __shared__ float smax[64][5];
    __shared__ float ssum[64][5];
    const int t = threadIdx.x;
    const int vloc = t / 5, q = t - vloc * 5;
    const int v = blockIdx.x * 64 + vloc;
    const bool active = (v < n);

    float r[8];
    if (active) {
        const uint4* tsv = (const uint4*)ts;   // row stride 64 bf16 = 8 uint4
        int beg = rowbeg[v], end = rowend[v];
        float acc[8];
        init_bf8(acc, tsv[(long long)v * 8 + q]);
        gather_pipe4<8>(tsv, csr, beg, end, q, acc);

        float dv = dis[v];
        float4 b0 = ((const float4*)b)[q * 2];
        float4 b1 = ((const float4*)b)[q * 2 + 1];
        r[0] = acc[0] * dv + b0.x;
        r[1] = acc[1] * dv + b0.y;
        r[2] = acc[2] * dv + b0.z;
        r[3] = acc[3] * dv + b0.w;
        r[4] = acc[4] * dv + b1.x;
        r[5] = acc[5] * dv + b1.y;
        r[6] = acc[6] * dv + b1.z;
        r[7] = acc[7] * dv + b1.w;
    } else {
#pragma unroll
        for (int i = 0; i < 8; ++i) r[i] = 0.0f;
    }

    float m = r[0];
#pragma unroll
    for (int i = 1; i < 8; ++i) m = fmaxf(m, r[i]);
    smax[vloc][q] = m;
    __syncthreads();
    float gm = fmaxf(fmaxf(fmaxf(smax[vloc][0], smax[vloc][1]), fmaxf(smax[vloc][2], smax[vloc][3])),
                     smax[vloc][4]);
    float s = 0.0f;
#pragma unroll
    for (int i = 0; i < 8; ++i) s += __expf(r[i] - gm);
    ssum[vloc][q] = s;
    __syncthreads();
    float tot = ssum[vloc][0] + ssum[vloc][1] + ssum[vloc][2] + ssum[vloc][3] + ssum[vloc][4];
    float c = gm + __logf(tot);

    if (active) {
        float* rp = out + (long long)v * OUT_DIM + q * 8;
        float4 o0 = { r[0] - c, r[1] - c, r[2] - c, r[3] - c };
        float4 o1 = { r[4] - c, r[5] - c, r[6] - c, r[7] - c };
        ((float4*)rp)[0] = o0;
        ((float4*)rp)[1] = o1;
    }
}

extern "C" void kernel_launch(void* const* d_in, const int* in_sizes, int n_in,
                              void* d_out, int out_size, void* d_ws, size_t ws_size,
                              hipStream_t stream) {
    const float* x  = (const float*)d_in[0];
    const int*   ei = (const int*)d_in[1];
    const float* W1 = (const float*)d_in[2];
    const float* b1 = (const float*)d_in[3];
    const float* W2 = (const float*)d_in[4];
    const float* b2 = (const float*)d_in[5];
    float* out = (float*)d_out;

    const int* src = ei;
    const int* dst = ei + N_EDGES;

    // workspace layout (bytes) — non-overlapping; csr/buk are CAP-padded (196*12288*4 = 9.63 MB)
    char* ws = (char*)d_ws;
    int*    rowbeg  = (int*)ws;                         // [0, 400K)
    int*    rowend  = (int*)(ws + (512 << 10));         // [512K, +400K)
    float*  dis     = (float*)(ws + (1024 << 10));      // [1024K, +400K)
    int*    cursorA = (int*)(ws + (1536 << 10));        // 784 B (RELATIVE counts)
    ushort* Wb2     = (ushort*)(ws + (1540 << 10));     // 6 KB
    int*    csr     = (int*)(ws + (2048 << 10));        // 9.63 MB
    char*   p       = ws + (12288 << 10);               // 12 MB
    ushort* ts1     = (ushort*)p;                       // 12.8 MB (bf16 [M][64], unscaled XW1)
    ushort* ts2     = (ushort*)(p + 12800000);          // 12.8 MB (bf16 [M][64], cols 0-47 used)
    uint*   buk     = (uint*)(p + 25600000);            // 9.63 MB

    // zero relative bucket cursors, then merged partA + GEMM1 + packW2 (co-scheduled)
    hipMemsetAsync(cursorA, 0, NBUK * sizeof(int), stream);
    merged_kernel<<<MERGE_BLOCKS, 256, 0, stream>>>(src, dst, cursorA, buk, W1, W2, Wb2,
                                                    x, ts1, N_NODES);

    // per-bucket CSR build
    bucket_kernel<<<NBUK, 512, 0, stream>>>(buk, cursorA, rowbeg, rowend, dis, csr, N_NODES);

    // fused: gather64 (dis-folded) + relu/bias -> LDS -> GEMM2 -> ts2 (128 B rows)
    fused64_kernel<<<(N_NODES + 31) / 32, 256, 0, stream>>>(rowbeg, rowend, csr, ts1, dis, b1,
                                                            Wb2, ts2, N_NODES);

    // layer 2 gather + log_softmax
    gather40ls_kernel<<<(N_NODES + 63) / 64, 320, 0, stream>>>(rowbeg, rowend, csr, ts2, dis,
                                                               b2, out, N_NODES);
}